// Round 4
// baseline (116.787 us; speedup 1.0000x reference)
//
#include <hip/hip_runtime.h>

// etp: out[n, coff(l3)+m3, u] = sum_p sum_{m1,m2} cg_p[m1,m2,m3] * Y[n, yoff(l1)+m1]
//                               * H[n, coff(l2)+m2, u] * W[n, p, u]
// N=16384 edges, 16 channels (l=0..3, dims 1,3,5,7), MUL=128.
//
// R3: same structure as R2 (float2, one wave per edge, 4 edges/block) but with
// __launch_bounds__(256, 4): VGPR cap 128 instead of the default-occupancy 64.
// R1/R2 showed the compiler pinning VGPRs to 84/64 and spilling/reloading the
// h[16]+acc[16] live set (~90 regs incl. addressing) -> latency-bound ~150us.
// With the cap raised the working set is genuinely register-resident.

#define BS 256
#define GSZ 64   // lanes per edge (one wave)
#define EPB 4    // edges per block
#define YD 16
#define HD 2048
#define WD 2944
#define NROW 99  // sum of d3 over paths (B rows, padded to 8 floats each)

// X(p, l1, l2, l3, cg_offset, row_offset)
#define FOR_PATHS(X) \
  X(0, 0,0,0,    0,  0) \
  X(1, 0,1,1,    1,  1) \
  X(2, 0,2,2,   10,  4) \
  X(3, 0,3,3,   35,  9) \
  X(4, 1,0,1,   84, 16) \
  X(5, 1,1,0,   93, 19) \
  X(6, 1,1,2,  102, 20) \
  X(7, 1,2,1,  147, 25) \
  X(8, 1,2,3,  192, 28) \
  X(9, 1,3,2,  297, 35) \
  X(10,2,0,2,  402, 40) \
  X(11,2,1,1,  427, 45) \
  X(12,2,1,3,  472, 48) \
  X(13,2,2,0,  577, 55) \
  X(14,2,2,2,  602, 56) \
  X(15,2,3,1,  727, 61) \
  X(16,2,3,3,  832, 64) \
  X(17,3,0,3, 1077, 71) \
  X(18,3,1,2, 1126, 78) \
  X(19,3,2,1, 1231, 83) \
  X(20,3,2,3, 1336, 86) \
  X(21,3,3,0, 1581, 93) \
  X(22,3,3,2, 1630, 94)

__host__ __device__ constexpr int coff(int l) {
  return l == 0 ? 0 : (l == 1 ? 1 : (l == 2 ? 4 : 9));
}

__global__ __launch_bounds__(BS, 4) void etp_kernel(
    const float* __restrict__ Y, const float* __restrict__ H,
    const float* __restrict__ W, const float* __restrict__ CG,
    float* __restrict__ O) {
  const int g = threadIdx.x >> 6;   // edge within block
  const int l = threadIdx.x & 63;   // lane within wave; owns u = 2l, 2l+1
  const int n = blockIdx.x * EPB + g;

  __shared__ __align__(16) float Bsm[EPB][NROW * 8];  // 12672 B
  __shared__ float ysm[EPB][YD];

  { const int t = threadIdx.x;
    if (t < EPB * YD) {
      const int e = t >> 4, c = t & 15;
      ysm[e][c] = Y[(size_t)(blockIdx.x * EPB + e) * YD + c];
    } }
  __syncthreads();

  // Phase 1: B_p[m3][m2] = sum_a cg_p[a,m2,m3] * y[coff(l1)+a], per edge.
  // d2*d3 <= 49 < 64 lanes -> single step per path.
#define BUILD(P, L1, L2, L3, CGO, RO) { \
    constexpr int d1 = 2*(L1)+1, d2 = 2*(L2)+1, d3 = 2*(L3)+1; \
    if (l < d2 * d3) { \
      const int m3 = l / d2, m2 = l - m3 * d2; \
      float s = 0.f; \
      _Pragma("unroll") \
      for (int a = 0; a < d1; ++a) \
        s += CG[(CGO) + (a * d2 + m2) * d3 + m3] * ysm[g][coff(L1) + a]; \
      Bsm[g][((RO) + m3) * 8 + m2] = s; \
    } }
  FOR_PATHS(BUILD)
#undef BUILD
  __syncthreads();

  // Phase 2: per-lane contraction over 2 u's (float2).
  const float2* __restrict__ Hp = (const float2*)(H + (size_t)n * HD);
  const float2* __restrict__ Wp = (const float2*)(W + (size_t)n * WD);
  float2* __restrict__ Op = (float2*)(O + (size_t)n * HD);

  float2 h[YD];
#pragma unroll
  for (int c = 0; c < YD; ++c) h[c] = Hp[c * GSZ + l];

  float2 acc[YD];
#pragma unroll
  for (int c = 0; c < YD; ++c) acc[c] = make_float2(0.f, 0.f);

#define DOPATH(P, L1, L2, L3, CGO, RO) { \
    constexpr int d2 = 2*(L2)+1, d3 = 2*(L3)+1; \
    const float2 wv = Wp[(P) * GSZ + l]; \
    _Pragma("unroll") \
    for (int m3 = 0; m3 < d3; ++m3) { \
      const float4* row = (const float4*)&Bsm[g][((RO) + m3) * 8]; \
      float br[8]; \
      *(float4*)&br[0] = row[0]; \
      if (d2 > 4) *(float4*)&br[4] = row[1]; \
      float2 s = make_float2(0.f, 0.f); \
      _Pragma("unroll") \
      for (int m2 = 0; m2 < d2; ++m2) { \
        const float b = br[m2]; \
        const float2 hv = h[coff(L2) + m2]; \
        s.x += b * hv.x; s.y += b * hv.y; \
      } \
      float2& A = acc[coff(L3) + m3]; \
      A.x += s.x * wv.x; A.y += s.y * wv.y; \
    } }
  FOR_PATHS(DOPATH)
#undef DOPATH

#pragma unroll
  for (int c = 0; c < YD; ++c) Op[c * GSZ + l] = acc[c];
}

extern "C" void kernel_launch(void* const* d_in, const int* in_sizes, int n_in,
                              void* d_out, int out_size, void* d_ws, size_t ws_size,
                              hipStream_t stream) {
  const float* Y  = (const float*)d_in[0];
  const float* H  = (const float*)d_in[1];
  const float* W  = (const float*)d_in[2];
  const float* CG = (const float*)d_in[3];
  float* O = (float*)d_out;

  const int n_edges = in_sizes[0] / YD;
  etp_kernel<<<n_edges / EPB, BS, 0, stream>>>(Y, H, W, CG, O);
}

// Round 5
// 114.968 us; speedup vs baseline: 1.0158x; 1.0158x over previous
//
#include <hip/hip_runtime.h>

// etp: out[n, coff(l3)+m3, u] = sum_p sum_{m1,m2} cg_p[m1,m2,m3] * Y[n, yoff(l1)+m1]
//                               * H[n, coff(l2)+m2, u] * W[n, p, u]
// N=16384 edges, 16 channels (l=0..3, dims 1,3,5,7), MUL=128.
//
// R4: float4 over u (32 lanes/edge, 8 edges per 256-block), with h[] PINNED in
// VGPRs via empty inline-asm. R1-R3 showed the compiler rematerializing the
// const/__restrict__ h loads instead of keeping them live (VGPR stuck at
// 64-84, latency-bound ~148us). Pinning makes remat illegal; launch_bounds
// (256,2) gives a 256-VGPR budget for the true ~200-reg live set.

#define BS 256
#define GSZ 32   // lanes per edge
#define EPB 8    // edges per block
#define YD 16
#define HD 2048
#define WD 2944
#define NROW 99  // sum of d3 over paths (B rows, padded to 8 floats each)

// X(p, l1, l2, l3, cg_offset, row_offset)
#define FOR_PATHS(X) \
  X(0, 0,0,0,    0,  0) \
  X(1, 0,1,1,    1,  1) \
  X(2, 0,2,2,   10,  4) \
  X(3, 0,3,3,   35,  9) \
  X(4, 1,0,1,   84, 16) \
  X(5, 1,1,0,   93, 19) \
  X(6, 1,1,2,  102, 20) \
  X(7, 1,2,1,  147, 25) \
  X(8, 1,2,3,  192, 28) \
  X(9, 1,3,2,  297, 35) \
  X(10,2,0,2,  402, 40) \
  X(11,2,1,1,  427, 45) \
  X(12,2,1,3,  472, 48) \
  X(13,2,2,0,  577, 55) \
  X(14,2,2,2,  602, 56) \
  X(15,2,3,1,  727, 61) \
  X(16,2,3,3,  832, 64) \
  X(17,3,0,3, 1077, 71) \
  X(18,3,1,2, 1126, 78) \
  X(19,3,2,1, 1231, 83) \
  X(20,3,2,3, 1336, 86) \
  X(21,3,3,0, 1581, 93) \
  X(22,3,3,2, 1630, 94)

__host__ __device__ constexpr int coff(int l) {
  return l == 0 ? 0 : (l == 1 ? 1 : (l == 2 ? 4 : 9));
}

__global__ __launch_bounds__(BS, 2) void etp_kernel(
    const float* __restrict__ Y, const float* __restrict__ H,
    const float* __restrict__ W, const float* __restrict__ CG,
    float* __restrict__ O) {
  const int g = threadIdx.x >> 5;   // edge within block
  const int l = threadIdx.x & 31;   // lane within edge-group; owns u = 4l..4l+3
  const int n = blockIdx.x * EPB + g;

  __shared__ __align__(16) float Bsm[EPB][NROW * 8];  // 25344 B
  __shared__ float ysm[EPB][YD];

  { const int t = threadIdx.x;
    if (t < EPB * YD) {
      const int e = t >> 4, c = t & 15;
      ysm[e][c] = Y[(size_t)(blockIdx.x * EPB + e) * YD + c];
    } }
  __syncthreads();

  // Phase 1: B_p[m3][m2] = sum_a cg_p[a,m2,m3] * y[coff(l1)+a], per edge.
#define BUILD(P, L1, L2, L3, CGO, RO) { \
    constexpr int d1 = 2*(L1)+1, d2 = 2*(L2)+1, d3 = 2*(L3)+1; \
    _Pragma("unroll") \
    for (int it = 0; it < (d2 * d3 + GSZ - 1) / GSZ; ++it) { \
      const int idx = l + it * GSZ; \
      if (idx < d2 * d3) { \
        const int m3 = idx / d2, m2 = idx - m3 * d2; \
        float s = 0.f; \
        _Pragma("unroll") \
        for (int a = 0; a < d1; ++a) \
          s += CG[(CGO) + (a * d2 + m2) * d3 + m3] * ysm[g][coff(L1) + a]; \
        Bsm[g][((RO) + m3) * 8 + m2] = s; \
      } } }
  FOR_PATHS(BUILD)
#undef BUILD
  __syncthreads();

  // Phase 2: per-lane contraction over 4 u's (float4), h pinned in VGPRs.
  const float4* __restrict__ Hp = (const float4*)(H + (size_t)n * HD);
  const float4* __restrict__ Wp = (const float4*)(W + (size_t)n * WD);
  float4* __restrict__ Op = (float4*)(O + (size_t)n * HD);

  float4 h[YD];
#pragma unroll
  for (int c = 0; c < YD; ++c) h[c] = Hp[c * GSZ + l];
#pragma unroll
  for (int c = 0; c < YD; ++c)
    asm volatile("" : "+v"(h[c].x), "+v"(h[c].y), "+v"(h[c].z), "+v"(h[c].w));

  float4 acc[YD];
#pragma unroll
  for (int c = 0; c < YD; ++c) acc[c] = make_float4(0.f, 0.f, 0.f, 0.f);

#define DOPATH(P, L1, L2, L3, CGO, RO) { \
    constexpr int d2 = 2*(L2)+1, d3 = 2*(L3)+1; \
    const float4 wv = Wp[(P) * GSZ + l]; \
    _Pragma("unroll") \
    for (int m3 = 0; m3 < d3; ++m3) { \
      const float4* row = (const float4*)&Bsm[g][((RO) + m3) * 8]; \
      float br[8]; \
      *(float4*)&br[0] = row[0]; \
      if (d2 > 4) *(float4*)&br[4] = row[1]; \
      float4 s = make_float4(0.f, 0.f, 0.f, 0.f); \
      _Pragma("unroll") \
      for (int m2 = 0; m2 < d2; ++m2) { \
        const float b = br[m2]; \
        const float4 hv = h[coff(L2) + m2]; \
        s.x += b * hv.x; s.y += b * hv.y; s.z += b * hv.z; s.w += b * hv.w; \
      } \
      float4& A = acc[coff(L3) + m3]; \
      A.x += s.x * wv.x; A.y += s.y * wv.y; A.z += s.z * wv.z; A.w += s.w * wv.w; \
    } }
  FOR_PATHS(DOPATH)
#undef DOPATH

#pragma unroll
  for (int c = 0; c < YD; ++c) Op[c * GSZ + l] = acc[c];
}

extern "C" void kernel_launch(void* const* d_in, const int* in_sizes, int n_in,
                              void* d_out, int out_size, void* d_ws, size_t ws_size,
                              hipStream_t stream) {
  const float* Y  = (const float*)d_in[0];
  const float* H  = (const float*)d_in[1];
  const float* W  = (const float*)d_in[2];
  const float* CG = (const float*)d_in[3];
  float* O = (float*)d_out;

  const int n_edges = in_sizes[0] / YD;
  etp_kernel<<<n_edges / EPB, BS, 0, stream>>>(Y, H, W, CG, O);
}

// Round 6
// 107.505 us; speedup vs baseline: 1.0863x; 1.0694x over previous
//
#include <hip/hip_runtime.h>

// etp: out[n, coff(l3)+m3, u] = sum_p sum_{m1,m2} cg_p[m1,m2,m3] * Y[n, yoff(l1)+m1]
//                               * H[n, coff(l2)+m2, u] * W[n, p, u]
// N=16384 edges, 16 channels (l=0..3, dims 1,3,5,7), MUL=128.
//
// R5: float4 over u (32 lanes/edge, 8 edges per 256-block).
// amdgpu_waves_per_eu(2,2): pins occupancy target at 2 waves/EU so the
// pre-RA scheduler budgets ~256 VGPRs instead of compacting to 80 (R1-R4
// were latency-bound on re-issued loads; every pipe <=25% busy).
// All 39 global loads (h[16]+w[23]) hoisted into one burst -> 39 KB in
// flight per wave, covers HBM latency at 2 waves/SIMD.
// Nontemporal output stores keep the 134 MB of writes from evicting
// H/W from L3 between graph replays.

#define BS 256
#define GSZ 32   // lanes per edge
#define EPB 8    // edges per block
#define YD 16
#define HD 2048
#define WD 2944
#define NP 23
#define NROW 99  // sum of d3 over paths (B rows, padded to 8 floats each)

typedef float f4 __attribute__((ext_vector_type(4)));

// X(p, l1, l2, l3, cg_offset, row_offset)
#define FOR_PATHS(X) \
  X(0, 0,0,0,    0,  0) \
  X(1, 0,1,1,    1,  1) \
  X(2, 0,2,2,   10,  4) \
  X(3, 0,3,3,   35,  9) \
  X(4, 1,0,1,   84, 16) \
  X(5, 1,1,0,   93, 19) \
  X(6, 1,1,2,  102, 20) \
  X(7, 1,2,1,  147, 25) \
  X(8, 1,2,3,  192, 28) \
  X(9, 1,3,2,  297, 35) \
  X(10,2,0,2,  402, 40) \
  X(11,2,1,1,  427, 45) \
  X(12,2,1,3,  472, 48) \
  X(13,2,2,0,  577, 55) \
  X(14,2,2,2,  602, 56) \
  X(15,2,3,1,  727, 61) \
  X(16,2,3,3,  832, 64) \
  X(17,3,0,3, 1077, 71) \
  X(18,3,1,2, 1126, 78) \
  X(19,3,2,1, 1231, 83) \
  X(20,3,2,3, 1336, 86) \
  X(21,3,3,0, 1581, 93) \
  X(22,3,3,2, 1630, 94)

__host__ __device__ constexpr int coff(int l) {
  return l == 0 ? 0 : (l == 1 ? 1 : (l == 2 ? 4 : 9));
}

__global__ __launch_bounds__(BS)
__attribute__((amdgpu_waves_per_eu(2, 2)))
void etp_kernel(
    const float* __restrict__ Y, const float* __restrict__ H,
    const float* __restrict__ W, const float* __restrict__ CG,
    float* __restrict__ O) {
  const int g = threadIdx.x >> 5;   // edge within block
  const int l = threadIdx.x & 31;   // lane within edge-group; owns u = 4l..4l+3
  const int n = blockIdx.x * EPB + g;

  __shared__ __align__(16) float Bsm[EPB][NROW * 8];  // 25344 B
  __shared__ float ysm[EPB][YD];

  { const int t = threadIdx.x;
    if (t < EPB * YD) {
      const int e = t >> 4, c = t & 15;
      ysm[e][c] = Y[(size_t)(blockIdx.x * EPB + e) * YD + c];
    } }
  __syncthreads();

  // Phase 1: B_p[m3][m2] = sum_a cg_p[a,m2,m3] * y[coff(l1)+a], per edge.
#define BUILD(P, L1, L2, L3, CGO, RO) { \
    constexpr int d1 = 2*(L1)+1, d2 = 2*(L2)+1, d3 = 2*(L3)+1; \
    _Pragma("unroll") \
    for (int it = 0; it < (d2 * d3 + GSZ - 1) / GSZ; ++it) { \
      const int idx = l + it * GSZ; \
      if (idx < d2 * d3) { \
        const int m3 = idx / d2, m2 = idx - m3 * d2; \
        float s = 0.f; \
        _Pragma("unroll") \
        for (int a = 0; a < d1; ++a) \
          s += CG[(CGO) + (a * d2 + m2) * d3 + m3] * ysm[g][coff(L1) + a]; \
        Bsm[g][((RO) + m3) * 8 + m2] = s; \
      } } }
  FOR_PATHS(BUILD)
#undef BUILD
  __syncthreads();

  // Phase 2: per-lane contraction over 4 u's (float4).
  const f4* __restrict__ Hp = (const f4*)(H + (size_t)n * HD);
  const f4* __restrict__ Wp = (const f4*)(W + (size_t)n * WD);
  f4* __restrict__ Op = (f4*)(O + (size_t)n * HD);

  // One burst of 39 16B loads: all h channels + all path weights.
  f4 h[YD];
#pragma unroll
  for (int c = 0; c < YD; ++c) h[c] = Hp[c * GSZ + l];
  f4 wv[NP];
#pragma unroll
  for (int p = 0; p < NP; ++p) wv[p] = Wp[p * GSZ + l];

  f4 acc[YD];
#pragma unroll
  for (int c = 0; c < YD; ++c) acc[c] = (f4)0.f;

#define DOPATH(P, L1, L2, L3, CGO, RO) { \
    constexpr int d2 = 2*(L2)+1, d3 = 2*(L3)+1; \
    _Pragma("unroll") \
    for (int m3 = 0; m3 < d3; ++m3) { \
      const f4* row = (const f4*)&Bsm[g][((RO) + m3) * 8]; \
      float br[8]; \
      *(f4*)&br[0] = row[0]; \
      if (d2 > 4) *(f4*)&br[4] = row[1]; \
      f4 s = (f4)0.f; \
      _Pragma("unroll") \
      for (int m2 = 0; m2 < d2; ++m2) \
        s += br[m2] * h[coff(L2) + m2]; \
      acc[coff(L3) + m3] += s * wv[P]; \
    } }
  FOR_PATHS(DOPATH)
#undef DOPATH

#pragma unroll
  for (int c = 0; c < YD; ++c)
    __builtin_nontemporal_store(acc[c], &Op[c * GSZ + l]);
}

extern "C" void kernel_launch(void* const* d_in, const int* in_sizes, int n_in,
                              void* d_out, int out_size, void* d_ws, size_t ws_size,
                              hipStream_t stream) {
  const float* Y  = (const float*)d_in[0];
  const float* H  = (const float*)d_in[1];
  const float* W  = (const float*)d_in[2];
  const float* CG = (const float*)d_in[3];
  float* O = (float*)d_out;

  const int n_edges = in_sizes[0] / YD;
  etp_kernel<<<n_edges / EPB, BS, 0, stream>>>(Y, H, W, CG, O);
}

// Round 8
// 106.570 us; speedup vs baseline: 1.0959x; 1.0088x over previous
//
#include <hip/hip_runtime.h>

// etp: out[n, coff(l3)+m3, u] = sum_p sum_{m1,m2} cg_p[m1,m2,m3] * Y[n, yoff(l1)+m1]
//                               * H[n, coff(l2)+m2, u] * W[n, p, u]
// N=16384 edges, 16 channels (l=0..3, dims 1,3,5,7), MUL=128.
//
// R7 = R6 (wave-independent persistent streams, software-pipelined) with the
// shfl-under-divergence bug fixed: y is broadcast to yy[16] by 16
// UNCONDITIONAL __shfl's (all lanes active) before the guarded B-write.
// R6's failure: __shfl source lanes were inactive inside if(l<d2*d3).
//
// One wave = one edge (float2, 64 lanes x 2u); each wave owns 8 edges:
// issue next edge's h/w loads -> build next edge's B (wave-private LDS
// double-buffer) -> compute current edge from registers -> store.
// No __syncthreads in the loop => no vmcnt(0) drain; next 19.5 KB burst
// is always in flight under compute.

#define BS 256
#define WPB 4     // waves per block
#define EPW 8     // edges per wave
#define YD 16
#define HD 2048
#define WD 2944
#define NP 23
#define NROW 99   // sum of d3 over paths (B rows, padded to 8 floats)
#define CGTOT 1875

typedef float f2 __attribute__((ext_vector_type(2)));
typedef float f4 __attribute__((ext_vector_type(4)));

// X(p, l1, l2, l3, cg_offset, row_offset)
#define FOR_PATHS(X) \
  X(0, 0,0,0,    0,  0) \
  X(1, 0,1,1,    1,  1) \
  X(2, 0,2,2,   10,  4) \
  X(3, 0,3,3,   35,  9) \
  X(4, 1,0,1,   84, 16) \
  X(5, 1,1,0,   93, 19) \
  X(6, 1,1,2,  102, 20) \
  X(7, 1,2,1,  147, 25) \
  X(8, 1,2,3,  192, 28) \
  X(9, 1,3,2,  297, 35) \
  X(10,2,0,2,  402, 40) \
  X(11,2,1,1,  427, 45) \
  X(12,2,1,3,  472, 48) \
  X(13,2,2,0,  577, 55) \
  X(14,2,2,2,  602, 56) \
  X(15,2,3,1,  727, 61) \
  X(16,2,3,3,  832, 64) \
  X(17,3,0,3, 1077, 71) \
  X(18,3,1,2, 1126, 78) \
  X(19,3,2,1, 1231, 83) \
  X(20,3,2,3, 1336, 86) \
  X(21,3,3,0, 1581, 93) \
  X(22,3,3,2, 1630, 94)

__host__ __device__ constexpr int coff(int l) {
  return l == 0 ? 0 : (l == 1 ? 1 : (l == 2 ? 4 : 9));
}

// Build B for one edge into Bdst (wave-private). yv: lane c (c<16) holds y[c].
__device__ __forceinline__ void build_edge(float* Bdst, const float* cgs,
                                           float yv, int l) {
  // Unconditional broadcast: all 64 lanes active, sources 0..15 active.
  float yy[YD];
#pragma unroll
  for (int c = 0; c < YD; ++c) yy[c] = __shfl(yv, c, 64);

#define BLD(P, L1, L2, L3, CGO, RO) { \
    constexpr int d1 = 2*(L1)+1, d2 = 2*(L2)+1, d3 = 2*(L3)+1; \
    if (l < d2 * d3) { \
      const int m3 = l / d2, m2 = l - m3 * d2; \
      float s = 0.f; \
      _Pragma("unroll") \
      for (int a = 0; a < d1; ++a) \
        s += cgs[(CGO) + (a * d2 + m2) * d3 + m3] * yy[coff(L1) + a]; \
      Bdst[((RO) + m3) * 8 + m2] = s; \
    } }
  FOR_PATHS(BLD)
#undef BLD
}

__device__ __forceinline__ void compute_edge(const float* Bsrc,
                                             const f2 (&h)[YD],
                                             const f2 (&w)[NP],
                                             f2 (&acc)[YD]) {
#pragma unroll
  for (int c = 0; c < YD; ++c) acc[c] = (f2)0.f;
#define DOP(P, L1, L2, L3, CGO, RO) { \
    constexpr int d2 = 2*(L2)+1, d3 = 2*(L3)+1; \
    const f2 wv = w[P]; \
    _Pragma("unroll") \
    for (int m3 = 0; m3 < d3; ++m3) { \
      const f4* row = (const f4*)&Bsrc[((RO) + m3) * 8]; \
      float br[8]; \
      *(f4*)&br[0] = row[0]; \
      if (d2 > 4) *(f4*)&br[4] = row[1]; \
      f2 s = (f2)0.f; \
      _Pragma("unroll") \
      for (int m2 = 0; m2 < d2; ++m2) \
        s += br[m2] * h[coff(L2) + m2]; \
      acc[coff(L3) + m3] += s * wv; \
    } }
  FOR_PATHS(DOP)
#undef DOP
}

__global__ __launch_bounds__(BS)
__attribute__((amdgpu_waves_per_eu(2, 2)))
void etp_kernel(const float* __restrict__ Yg, const float* __restrict__ Hg,
                const float* __restrict__ Wg, const float* __restrict__ CGg,
                float* __restrict__ Og) {
  __shared__ float cgs[CGTOT];                       // 7.5 KB
  __shared__ __align__(16) float Bsm[WPB][2][NROW * 8];  // 25.3 KB

  for (int i = threadIdx.x; i < CGTOT; i += BS) cgs[i] = CGg[i];

  const int wid = threadIdx.x >> 6;
  const int l = threadIdx.x & 63;
  const size_t ebase = ((size_t)blockIdx.x * WPB + wid) * EPW;
  float* Bw = &Bsm[wid][0][0];

  __syncthreads();  // cgs ready (only barrier in the kernel)

  // Prologue: build B for edge 0 into buf0; load y of edge 1; burst h/w of edge 0.
  float yA = Yg[ebase * YD + (l & 15)];
  build_edge(Bw, cgs, yA, l);
  yA = Yg[(ebase + 1) * YD + (l & 15)];

  f2 ha[YD], wa[NP], hb[YD], wb[NP], acc[YD];
  { const f2* Hp = (const f2*)(Hg + ebase * HD);
    const f2* Wp = (const f2*)(Wg + ebase * WD);
#pragma unroll
    for (int c = 0; c < YD; ++c) ha[c] = Hp[c * 64 + l];
#pragma unroll
    for (int p = 0; p < NP; ++p) wa[p] = Wp[p * 64 + l]; }

  // Steady state: prefetch e+1 (regs) || build B(e+1) || compute e || store e.
#define STEP(EV, CBUF, HC, WC, HN, WN) { \
    const int e = (EV); \
    if (e + 1 < EPW) { \
      const f2* HpN = (const f2*)(Hg + (ebase + e + 1) * HD); \
      const f2* WpN = (const f2*)(Wg + (ebase + e + 1) * WD); \
      _Pragma("unroll") for (int c = 0; c < YD; ++c) HN[c] = HpN[c * 64 + l]; \
      _Pragma("unroll") for (int p = 0; p < NP; ++p) WN[p] = WpN[p * 64 + l]; \
    } \
    float yB = Yg[(ebase + (e + 2 < EPW ? e + 2 : EPW - 1)) * YD + (l & 15)]; \
    if (e + 1 < EPW) \
      build_edge(Bw + (1 - (CBUF)) * (NROW * 8), cgs, yA, l); \
    compute_edge(Bw + (CBUF) * (NROW * 8), HC, WC, acc); \
    { f2* Op = (f2*)(Og + (ebase + e) * HD); \
      _Pragma("unroll") for (int c = 0; c < YD; ++c) \
        __builtin_nontemporal_store(acc[c], &Op[c * 64 + l]); } \
    yA = yB; \
  }

#pragma unroll 1
  for (int k = 0; k < EPW / 2; ++k) {
    STEP(2 * k,     0, ha, wa, hb, wb)
    STEP(2 * k + 1, 1, hb, wb, ha, wa)
  }
#undef STEP
}

extern "C" void kernel_launch(void* const* d_in, const int* in_sizes, int n_in,
                              void* d_out, int out_size, void* d_ws, size_t ws_size,
                              hipStream_t stream) {
  const float* Y  = (const float*)d_in[0];
  const float* H  = (const float*)d_in[1];
  const float* W  = (const float*)d_in[2];
  const float* CG = (const float*)d_in[3];
  float* O = (float*)d_out;

  const int n_edges = in_sizes[0] / YD;          // 16384
  const int blocks = n_edges / (WPB * EPW);      // 512
  etp_kernel<<<blocks, BS, 0, stream>>>(Y, H, W, CG, O);
}

// Round 9
// 101.886 us; speedup vs baseline: 1.1463x; 1.0460x over previous
//
#include <hip/hip_runtime.h>

// etp: out[n, coff(l3)+m3, u] = sum_p sum_{m1,m2} cg_p[m1,m2,m3] * Y[n, yoff(l1)+m1]
//                               * H[n, coff(l2)+m2, u] * W[n, p, u]
// N=16384 edges, 16 channels (l=0..3, dims 1,3,5,7), MUL=128.
//
// R8: max-TLP lean kernel. One thread = one u (scalar), 128 threads/edge,
// 2 edges per 256-thread block, 8192 blocks. Paths processed grouped by l2
// so only d2 (<=7) h values are live at a time -> ~40 live VGPRs;
// __launch_bounds__(256,8) forces <=64 VGPR = 8 waves/EU (32 waves/CU).
// R1-R7 bought per-wave ILP by sacrificing occupancy and the register
// allocator defeated the ILP every time (VGPR stuck at 64-128, loads sunk);
// this round hands latency hiding to the wave scheduler instead.
// B broadcast rows read as b128 (158/thread, vs R0's 565 scalar reads).

#define BS 256
#define EPB 2     // edges per block
#define TPE 128   // threads per edge
#define YD 16
#define HD 2048
#define WD 2944
#define NROW 99   // sum of d3 over paths (B rows, padded to 8 floats)

typedef float f4 __attribute__((ext_vector_type(4)));

// X(p, l1, l2, l3, cg_offset, row_offset) — build order (any)
#define FOR_PATHS(X) \
  X(0, 0,0,0,    0,  0) \
  X(1, 0,1,1,    1,  1) \
  X(2, 0,2,2,   10,  4) \
  X(3, 0,3,3,   35,  9) \
  X(4, 1,0,1,   84, 16) \
  X(5, 1,1,0,   93, 19) \
  X(6, 1,1,2,  102, 20) \
  X(7, 1,2,1,  147, 25) \
  X(8, 1,2,3,  192, 28) \
  X(9, 1,3,2,  297, 35) \
  X(10,2,0,2,  402, 40) \
  X(11,2,1,1,  427, 45) \
  X(12,2,1,3,  472, 48) \
  X(13,2,2,0,  577, 55) \
  X(14,2,2,2,  602, 56) \
  X(15,2,3,1,  727, 61) \
  X(16,2,3,3,  832, 64) \
  X(17,3,0,3, 1077, 71) \
  X(18,3,1,2, 1126, 78) \
  X(19,3,2,1, 1231, 83) \
  X(20,3,2,3, 1336, 86) \
  X(21,3,3,0, 1581, 93) \
  X(22,3,3,2, 1630, 94)

__host__ __device__ constexpr int coff(int l) {
  return l == 0 ? 0 : (l == 1 ? 1 : (l == 2 ? 4 : 9));
}

__global__ __launch_bounds__(BS, 8) void etp_kernel(
    const float* __restrict__ Y, const float* __restrict__ H,
    const float* __restrict__ W, const float* __restrict__ CG,
    float* __restrict__ O) {
  const int g = threadIdx.x >> 7;    // edge within block
  const int u = threadIdx.x & 127;   // u index (= lane pattern within 2 waves)
  const size_t n = (size_t)blockIdx.x * EPB + g;

  __shared__ __align__(16) float Bsm[EPB][NROW * 8];  // 6336 B
  __shared__ float ysm[EPB][YD];

  { const int t = threadIdx.x;
    if (t < EPB * YD) {
      const int e = t >> 4, c = t & 15;
      ysm[e][c] = Y[(size_t)(blockIdx.x * EPB + e) * YD + c];
    } }
  __syncthreads();

  // Phase 1: B_p[m3][m2] = sum_a cg_p[a,m2,m3] * y[coff(l1)+a], per edge.
#define BUILD(P, L1, L2, L3, CGO, RO) { \
    constexpr int d1 = 2*(L1)+1, d2 = 2*(L2)+1, d3 = 2*(L3)+1; \
    if (u < d2 * d3) { \
      const int m3 = u / d2, m2 = u - m3 * d2; \
      float s = 0.f; \
      _Pragma("unroll") \
      for (int a = 0; a < d1; ++a) \
        s += CG[(CGO) + (a * d2 + m2) * d3 + m3] * ysm[g][coff(L1) + a]; \
      Bsm[g][((RO) + m3) * 8 + m2] = s; \
    } }
  FOR_PATHS(BUILD)
#undef BUILD
  __syncthreads();

  // Phase 2: scalar per-u contraction, paths grouped by l2 so h live range
  // is short (d2 <= 7 floats at a time).
  const float* __restrict__ Hn = H + n * HD + u;
  const float* __restrict__ Wn = W + n * WD + u;
  float* __restrict__ On = O + n * HD + u;

  float acc[YD];
#pragma unroll
  for (int c = 0; c < YD; ++c) acc[c] = 0.f;

  // One path: rows (RO+m3), d2 entries each, times hh[], times w.
#define DOP(P, L2, L3, RO) { \
    constexpr int d2 = 2*(L2)+1, d3 = 2*(L3)+1; \
    const float wv = Wn[(P) * TPE]; \
    _Pragma("unroll") \
    for (int m3 = 0; m3 < d3; ++m3) { \
      const f4* row = (const f4*)&Bsm[g][((RO) + m3) * 8]; \
      float br[8]; \
      *(f4*)&br[0] = row[0]; \
      if (d2 > 4) *(f4*)&br[4] = row[1]; \
      float s = 0.f; \
      _Pragma("unroll") \
      for (int m2 = 0; m2 < d2; ++m2) s += br[m2] * hh[m2]; \
      acc[coff(L3) + m3] += s * wv; \
    } }

  { // l2 = 0 group: paths 0,4,10,17
    float hh[1];
    hh[0] = Hn[(coff(0) + 0) * TPE];
    DOP(0, 0, 0, 0)  DOP(4, 0, 1, 16)  DOP(10, 0, 2, 40)  DOP(17, 0, 3, 71)
  }
  { // l2 = 1 group: paths 1,5,6,11,12,18
    float hh[3];
#pragma unroll
    for (int m = 0; m < 3; ++m) hh[m] = Hn[(coff(1) + m) * TPE];
    DOP(1, 1, 1, 1)  DOP(5, 1, 0, 19)  DOP(6, 1, 2, 20)
    DOP(11, 1, 1, 45)  DOP(12, 1, 3, 48)  DOP(18, 1, 2, 78)
  }
  { // l2 = 2 group: paths 2,7,8,13,14,19,20
    float hh[5];
#pragma unroll
    for (int m = 0; m < 5; ++m) hh[m] = Hn[(coff(2) + m) * TPE];
    DOP(2, 2, 2, 4)  DOP(7, 2, 1, 25)  DOP(8, 2, 3, 28)
    DOP(13, 2, 0, 55)  DOP(14, 2, 2, 56)  DOP(19, 2, 1, 83)  DOP(20, 2, 3, 86)
  }
  { // l2 = 3 group: paths 3,9,15,16,21,22
    float hh[7];
#pragma unroll
    for (int m = 0; m < 7; ++m) hh[m] = Hn[(coff(3) + m) * TPE];
    DOP(3, 3, 3, 9)  DOP(9, 3, 2, 35)  DOP(15, 3, 1, 61)
    DOP(16, 3, 3, 64)  DOP(21, 3, 0, 93)  DOP(22, 3, 2, 94)
  }
#undef DOP

#pragma unroll
  for (int c = 0; c < YD; ++c)
    __builtin_nontemporal_store(acc[c], &On[c * TPE]);
}

extern "C" void kernel_launch(void* const* d_in, const int* in_sizes, int n_in,
                              void* d_out, int out_size, void* d_ws, size_t ws_size,
                              hipStream_t stream) {
  const float* Y  = (const float*)d_in[0];
  const float* H  = (const float*)d_in[1];
  const float* W  = (const float*)d_in[2];
  const float* CG = (const float*)d_in[3];
  float* O = (float*)d_out;

  const int n_edges = in_sizes[0] / YD;        // 16384
  etp_kernel<<<n_edges / EPB, BS, 0, stream>>>(Y, H, W, CG, O);
}